// Round 2
// 618.147 us; speedup vs baseline: 1.0293x; 1.0293x over previous
//
#include <hip/hip_runtime.h>

// ---------------- problem constants ----------------
#define T 4096          // tokens (2*2048)
#define Hdim 1024       // hidden
#define Idim 4096       // intermediate
#define NE 8            // experts
#define OUT0 4194304    // T*Hdim (out elems), logits follow at d_out+OUT0 (T*NE)
#define SPLITK 2        // gemm2 split-K factor (disjoint bf16 partials, no atomics)
#define BK 64           // GEMM K-tile (32 KB LDS total, 2 MFMA k-steps per barrier)

// padded slot capacity: sum ceil(cnt_e/128)*128 <= 8192 + 8*128 = 9216
#define SLOT_CAP 9216

// ---------------- ws layout (bytes) ----------------
#define W1B_OFF 0u                    // bf16 w1 [E][I][H]   67108864
#define W2B_OFF 67108864u             // bf16 w2 [E][H][I]   67108864
#define XB_OFF  134217728u            // bf16 x  [T][H]       8388608
#define HB_OFF  142606336u            // bf16 h  [SLOT_CAP][I] 75497472
#define YB_OFF  218103808u            // bf16 y  [2][SLOT_CAP][H] 37748736
#define META_OFF 255852544u
// meta (int index):
#define M_COUNTS 0      // [8]
#define M_CURS   8      // [8]
#define M_OFFS   16     // [9]  (unused; offsets computed inline)
#define M_TEXP   32     // [8192] token-pair -> expert
#define M_TSLOT  8224   // [8192] token-pair -> slot
#define M_STOK   16416  // [9216] slot -> token (-1 = pad)
#define M_TWF    25632  // float[8192] token-pair weight (reinterpret)

typedef short bf16x8 __attribute__((ext_vector_type(8)));
typedef float f32x4  __attribute__((ext_vector_type(4)));

__device__ __forceinline__ unsigned short f2bf(float f) {
    unsigned int b = __float_as_uint(f);
    b += 0x7fffu + ((b >> 16) & 1u);      // round-nearest-even
    return (unsigned short)(b >> 16);
}
__device__ __forceinline__ float bf2f(unsigned short s) {
    return __uint_as_float(((unsigned int)s) << 16);
}

// async global->LDS DMA, 16B/lane. LDS dest is wave-uniform base + lane*16
// (m104); our layout is linear-in-lane with the XOR swizzle pre-applied to the
// GLOBAL source address (rule #21: both-sides-or-neither), so content is
// identical to the verified reg-staged path.
#define GLD(gsrc, ldst) \
    __builtin_amdgcn_global_load_lds( \
        (const __attribute__((address_space(1))) unsigned int*)(gsrc), \
        (__attribute__((address_space(3))) unsigned int*)(ldst), 16, 0, 0)

// one launch converts both weight tensors fp32->bf16; also zeroes meta
// (counts/curs, stok pad markers) -- disjoint writes, all happen-before
// router_k via stream order. Folds the old zero_k launch away.
__global__ void cvt_w_k(const float* __restrict__ w1, const float* __restrict__ w2,
                        unsigned short* __restrict__ w1b, unsigned short* __restrict__ w2b,
                        int n4each, int* __restrict__ meta) {
    int i = blockIdx.x * blockDim.x + threadIdx.x;
    if (i < 16) meta[M_COUNTS + i] = 0;          // counts + cursors
    if (i < SLOT_CAP) meta[M_STOK + i] = -1;     // slot_token pad marker
    const float4* src; ushort4* dst; int j;
    if (i < n4each) { src = (const float4*)w1; dst = (ushort4*)w1b; j = i; }
    else            { src = (const float4*)w2; dst = (ushort4*)w2b; j = i - n4each; }
    float4 v = src[j];
    ushort4 o;
    o.x = f2bf(v.x); o.y = f2bf(v.y); o.z = f2bf(v.z); o.w = f2bf(v.w);
    dst[j] = o;
}

// fp32-exact router: logits, top-2, softmax, counts; also emits xb (bf16 x).
__global__ void router_k(const float* __restrict__ x, const float* __restrict__ gw,
                         float* __restrict__ logits_out, int* __restrict__ texp,
                         float* __restrict__ twf, int* __restrict__ counts,
                         unsigned short* __restrict__ xb) {
    int wv = threadIdx.x >> 6, lane = threadIdx.x & 63;
    int t = blockIdx.x * 4 + wv;
    const float* xp = x + (size_t)t * Hdim;
    unsigned short* xbp = xb + (size_t)t * Hdim;
    float s[NE];
    #pragma unroll
    for (int e = 0; e < NE; e++) s[e] = 0.f;
    #pragma unroll
    for (int j = 0; j < 16; j++) {
        float xv = xp[lane + 64 * j];
        xbp[lane + 64 * j] = f2bf(xv);
        #pragma unroll
        for (int e = 0; e < NE; e++) s[e] += xv * gw[e * Hdim + lane + 64 * j];
    }
    #pragma unroll
    for (int e = 0; e < NE; e++) {
        #pragma unroll
        for (int off = 32; off > 0; off >>= 1) s[e] += __shfl_xor(s[e], off);
    }
    if (lane == 0) {
        #pragma unroll
        for (int e = 0; e < NE; e++) logits_out[t * NE + e] = s[e];
        int i0 = 0; float v0 = s[0];
        #pragma unroll
        for (int e = 1; e < NE; e++) if (s[e] > v0) { v0 = s[e]; i0 = e; }
        int i1 = -1; float v1 = -3.4e38f;
        #pragma unroll
        for (int e = 0; e < NE; e++) if (e != i0 && s[e] > v1) { v1 = s[e]; i1 = e; }
        float e1 = expf(v1 - v0);            // v1<=v0, stable
        float inv = 1.f / (1.f + e1);
        texp[2 * t] = i0; texp[2 * t + 1] = i1;
        twf[2 * t] = inv; twf[2 * t + 1] = e1 * inv;
        atomicAdd(&counts[i0], 1);
        atomicAdd(&counts[i1], 1);
    }
}

// padded prefix-sum over counts is computed inline (deterministic, identical
// formula everywhere) -- deletes the serial 1-thread offsets_k launch.
__global__ void assign_k(const int* __restrict__ texp, const int* __restrict__ counts,
                         int* __restrict__ curs, int* __restrict__ stok, int* __restrict__ tslot) {
    int p = blockIdx.x * blockDim.x + threadIdx.x;  // pair id < 8192
    int e = texp[p];
    int off = 0;
    #pragma unroll
    for (int q = 0; q < NE; q++) {
        int pc = (counts[q] + 127) & ~127;
        off += (q < e) ? pc : 0;
    }
    int slot = off + atomicAdd(&curs[e], 1);
    stok[slot] = p >> 1;
    tslot[p] = slot;
}

// ---------------- grouped GEMM1: h = gelu(x @ w1[e]^T), bf16 out ----------------
// m97-style structure: direct async global->LDS (global_load_lds_dwordx4) with
// the XOR swizzle pre-applied to the per-lane GLOBAL address and a linear LDS
// destination (wave-uniform base + lane*16). No prefetch registers, no
// PF_STORE VALU phase -> fewer VGPRs -> 3 blocks/CU; cross-block wave overlap
// hides the vmcnt(0)+barrier drain (m114/m151: 874 vs 646 TF at 128^2).
__global__ __launch_bounds__(256, 3) void gemm1_k(
    const unsigned short* __restrict__ xb, const unsigned short* __restrict__ w1b,
    const int* __restrict__ counts, const int* __restrict__ stok,
    unsigned short* __restrict__ hb) {
    __shared__ __align__(16) unsigned short As[128 * BK];
    __shared__ __align__(16) unsigned short Bs[128 * BK];
    const int rt = blockIdx.y, ct = blockIdx.x;
    const int row0 = rt * 128;
    int offs[NE + 1];
    offs[0] = 0;
    #pragma unroll
    for (int q = 0; q < NE; q++) offs[q + 1] = offs[q] + ((counts[q] + 127) & ~127);
    if (row0 >= offs[NE]) return;
    int e = 0;
    #pragma unroll
    for (int q = 1; q < NE; q++) if (offs[q] <= row0) e = q;

    const int tid = threadIdx.x;
    const int lane = tid & 63, wv = tid >> 6;
    const int srow = lane >> 3;                 // row within 8-row staging group
    const int schunk = (lane & 7) ^ srow;       // swizzled source k-chunk (8 bf16)

    const unsigned short* gA[4];
    const unsigned short* gB[4];
    unsigned short* lA[4];
    unsigned short* lB[4];
    #pragma unroll
    for (int g = 0; g < 4; g++) {
        int r = wv * 32 + g * 8 + srow;
        int t = stok[row0 + r]; if (t < 0) t = 0;
        gA[g] = xb + (size_t)t * Hdim + schunk * 8;
        gB[g] = w1b + ((size_t)e * Idim + ct * 128 + r) * Hdim + schunk * 8;
        lA[g] = As + (wv * 32 + g * 8) * BK;    // wave-uniform LDS base
        lB[g] = Bs + (wv * 32 + g * 8) * BK;
    }

    f32x4 acc[4][4] = {};
    const int mrow = (wv & 1) * 64, ncol = (wv >> 1) * 64;
    const int fr = lane & 15, qd = lane >> 4;

    const int NIT = Hdim / BK;
    for (int it = 0; it < NIT; it++) {
        #pragma unroll
        for (int g = 0; g < 4; g++) {
            GLD(gA[g] + it * BK, lA[g]);
            GLD(gB[g] + it * BK, lB[g]);
        }
        __syncthreads();                      // vmcnt(0) drain -> tile resident
        #pragma unroll
        for (int ko = 0; ko < 2; ko++) {
            bf16x8 af[4], bff[4];
            #pragma unroll
            for (int mi = 0; mi < 4; mi++)
                af[mi]  = *(const bf16x8*)&As[(mrow + mi * 16 + fr) * BK + ((((ko << 2) | qd) ^ (fr & 7)) << 3)];
            #pragma unroll
            for (int ni = 0; ni < 4; ni++)
                bff[ni] = *(const bf16x8*)&Bs[(ncol + ni * 16 + fr) * BK + ((((ko << 2) | qd) ^ (fr & 7)) << 3)];
            #pragma unroll
            for (int mi = 0; mi < 4; mi++)
                #pragma unroll
                for (int ni = 0; ni < 4; ni++)
                    acc[mi][ni] = __builtin_amdgcn_mfma_f32_16x16x32_bf16(af[mi], bff[ni], acc[mi][ni], 0, 0, 0);
        }
        __syncthreads();                      // waves done reading before overwrite
    }
    // epilogue: tanh-form gelu (sigmoid identity) -> bf16.
    #pragma unroll
    for (int mi = 0; mi < 4; mi++) {
        #pragma unroll
        for (int ni = 0; ni < 4; ni++) {
            #pragma unroll
            for (int r = 0; r < 4; r++) {
                int row = row0 + mrow + mi * 16 + qd * 4 + r;
                int col = ct * 128 + ncol + ni * 16 + fr;
                float v = acc[mi][ni][r];
                float u = v * (1.f + 0.044715f * v * v);
                float g = v / (1.f + __expf(-1.5957691216f * u));
                hb[(size_t)row * Idim + col] = f2bf(g);
            }
        }
    }
}

// ---------------- grouped GEMM2 (split-K, disjoint partials): yk = h @ w2[e]^T ----------------
// 1D grid 1152, XCD-territory decode: XCD k = id%8 owns rt in [9k, 9k+9) for all
// (ct, kz) -> h fetched once per rt; w2 per-XCD-expert. Same DMA staging.
__global__ __launch_bounds__(256, 3) void gemm2_k(
    const unsigned short* __restrict__ hb, const unsigned short* __restrict__ w2b,
    const int* __restrict__ counts, unsigned short* __restrict__ y16) {
    __shared__ __align__(16) unsigned short As[128 * BK];
    __shared__ __align__(16) unsigned short Bs[128 * BK];
    const int id = blockIdx.x;
    const int k8 = id & 7;                 // intended XCD
    const int j  = id >> 3;                // per-XCD sequence 0..143
    const int ct = j & 7;                  // B col tile
    const int j8 = j >> 3;                 // 0..17
    const int rtL = j8 % 9, kz = j8 / 9;
    const int rt = k8 * 9 + rtL;
    const int row0 = rt * 128;
    int offs[NE + 1];
    offs[0] = 0;
    #pragma unroll
    for (int q = 0; q < NE; q++) offs[q + 1] = offs[q] + ((counts[q] + 127) & ~127);
    if (row0 >= offs[NE]) return;
    int e = 0;
    #pragma unroll
    for (int q = 1; q < NE; q++) if (offs[q] <= row0) e = q;

    const int tid = threadIdx.x;
    const int lane = tid & 63, wv = tid >> 6;
    const int srow = lane >> 3;
    const int schunk = (lane & 7) ^ srow;

    const unsigned short* gA[4];
    const unsigned short* gB[4];
    unsigned short* lA[4];
    unsigned short* lB[4];
    #pragma unroll
    for (int g = 0; g < 4; g++) {
        int r = wv * 32 + g * 8 + srow;
        gA[g] = hb + (size_t)(row0 + r) * Idim + schunk * 8;
        gB[g] = w2b + ((size_t)e * Hdim + ct * 128 + r) * Idim + schunk * 8;
        lA[g] = As + (wv * 32 + g * 8) * BK;
        lB[g] = Bs + (wv * 32 + g * 8) * BK;
    }

    f32x4 acc[4][4] = {};
    const int mrow = (wv & 1) * 64, ncol = (wv >> 1) * 64;
    const int fr = lane & 15, qd = lane >> 4;

    const int k0 = kz * (Idim / SPLITK);
    const int NIT = (Idim / SPLITK) / BK;
    for (int it = 0; it < NIT; it++) {
        #pragma unroll
        for (int g = 0; g < 4; g++) {
            GLD(gA[g] + k0 + it * BK, lA[g]);
            GLD(gB[g] + k0 + it * BK, lB[g]);
        }
        __syncthreads();
        #pragma unroll
        for (int ko = 0; ko < 2; ko++) {
            bf16x8 af[4], bff[4];
            #pragma unroll
            for (int mi = 0; mi < 4; mi++)
                af[mi]  = *(const bf16x8*)&As[(mrow + mi * 16 + fr) * BK + ((((ko << 2) | qd) ^ (fr & 7)) << 3)];
            #pragma unroll
            for (int ni = 0; ni < 4; ni++)
                bff[ni] = *(const bf16x8*)&Bs[(ncol + ni * 16 + fr) * BK + ((((ko << 2) | qd) ^ (fr & 7)) << 3)];
            #pragma unroll
            for (int mi = 0; mi < 4; mi++)
                #pragma unroll
                for (int ni = 0; ni < 4; ni++)
                    acc[mi][ni] = __builtin_amdgcn_mfma_f32_16x16x32_bf16(af[mi], bff[ni], acc[mi][ni], 0, 0, 0);
        }
        __syncthreads();
    }
    unsigned short* yk = y16 + (size_t)kz * SLOT_CAP * Hdim;
    #pragma unroll
    for (int mi = 0; mi < 4; mi++) {
        #pragma unroll
        for (int ni = 0; ni < 4; ni++) {
            #pragma unroll
            for (int r = 0; r < 4; r++) {
                int row = row0 + mrow + mi * 16 + qd * 4 + r;
                int col = ct * 128 + ncol + ni * 16 + fr;
                yk[(size_t)row * Hdim + col] = f2bf(acc[mi][ni][r]);
            }
        }
    }
}

// out[t] = w0 * (y0[s0]+y1[s0]) + w1 * (y0[s1]+y1[s1])   (bf16 partials, fused reduce)
__global__ void combine_k(const unsigned short* __restrict__ y16, const int* __restrict__ tslot,
                          const float* __restrict__ twf, float* __restrict__ out) {
    int i = blockIdx.x * blockDim.x + threadIdx.x;   // < T*H/8
    int t = i >> 7, rem = i & 127;                   // H/8 = 128
    int s0 = tslot[2 * t], s1 = tslot[2 * t + 1];
    float w0 = twf[2 * t], w1 = twf[2 * t + 1];
    const uint4* y0 = (const uint4*)(y16);
    const uint4* y1 = (const uint4*)(y16 + (size_t)SLOT_CAP * Hdim);
    uint4 a0 = y0[(size_t)s0 * 128 + rem];
    uint4 a1 = y1[(size_t)s0 * 128 + rem];
    uint4 b0 = y0[(size_t)s1 * 128 + rem];
    uint4 b1 = y1[(size_t)s1 * 128 + rem];
    float o[8];
    #pragma unroll
    for (int j = 0; j < 4; j++) {
        unsigned int ua0 = ((const unsigned int*)&a0)[j], ua1 = ((const unsigned int*)&a1)[j];
        unsigned int ub0 = ((const unsigned int*)&b0)[j], ub1 = ((const unsigned int*)&b1)[j];
        float alo = bf2f((unsigned short)ua0) + bf2f((unsigned short)ua1);
        float ahi = bf2f((unsigned short)(ua0 >> 16)) + bf2f((unsigned short)(ua1 >> 16));
        float blo = bf2f((unsigned short)ub0) + bf2f((unsigned short)ub1);
        float bhi = bf2f((unsigned short)(ub0 >> 16)) + bf2f((unsigned short)(ub1 >> 16));
        o[2 * j]     = w0 * alo + w1 * blo;
        o[2 * j + 1] = w0 * ahi + w1 * bhi;
    }
    float4* out4 = (float4*)out;
    out4[2 * i]     = make_float4(o[0], o[1], o[2], o[3]);
    out4[2 * i + 1] = make_float4(o[4], o[5], o[6], o[7]);
}

extern "C" void kernel_launch(void* const* d_in, const int* in_sizes, int n_in,
                              void* d_out, int out_size, void* d_ws, size_t ws_size,
                              hipStream_t stream) {
    const float* x  = (const float*)d_in[0];   // [2,2048,1024]
    const float* gw = (const float*)d_in[1];   // [8,1024]
    const float* w1 = (const float*)d_in[2];   // [8,4096,1024]
    const float* w2 = (const float*)d_in[3];   // [8,1024,4096]
    float* out = (float*)d_out;

    char* ws = (char*)d_ws;
    unsigned short* w1b = (unsigned short*)(ws + W1B_OFF);
    unsigned short* w2b = (unsigned short*)(ws + W2B_OFF);
    unsigned short* xb  = (unsigned short*)(ws + XB_OFF);
    unsigned short* hb  = (unsigned short*)(ws + HB_OFF);
    unsigned short* y16 = (unsigned short*)(ws + YB_OFF);
    int*            meta = (int*)(ws + META_OFF);
    int* counts = meta + M_COUNTS;
    int* curs   = meta + M_CURS;
    int* texp   = meta + M_TEXP;
    int* tslot  = meta + M_TSLOT;
    int* stok   = meta + M_STOK;
    float* twf  = (float*)(meta + M_TWF);

    cvt_w_k<<<65536, 256, 0, stream>>>(w1, w2, w1b, w2b, NE * Idim * Hdim / 4, meta);
    router_k<<<T / 4, 256, 0, stream>>>(x, gw, out + OUT0, texp, twf, counts, xb);
    assign_k<<<32, 256, 0, stream>>>(texp, counts, curs, stok, tslot);
    gemm1_k<<<dim3(Idim / 128, SLOT_CAP / 128), 256, 0, stream>>>(xb, w1b, counts, stok, hb);
    gemm2_k<<<(Hdim / 128) * (SLOT_CAP / 128) * SPLITK, 256, 0, stream>>>(hb, w2b, counts, y16);
    combine_k<<<T * Hdim / 8 / 256, 256, 0, stream>>>(y16, tslot, twf, out);
}